// Round 7
// baseline (460.279 us; speedup 1.0000x reference)
//
#include <hip/hip_runtime.h>

#define Bn 2
#define Ln 4096
#define Hn 8
#define Dn 64
#define NMEGA 32           // 128-key mega-tiles
#define BH_STRIDE 262144   // halves per bh in kp/vp

typedef float    f32x4  __attribute__((ext_vector_type(4)));
typedef float    f32x16 __attribute__((ext_vector_type(16)));
typedef _Float16 f16x2  __attribute__((ext_vector_type(2)));
typedef _Float16 f16x8  __attribute__((ext_vector_type(8)));
typedef unsigned int u32;
typedef u32 u32x2 __attribute__((ext_vector_type(2)));
typedef u32 u32x4 __attribute__((ext_vector_type(4)));

static __device__ __forceinline__ u32 pkf16(float a, float b){
    auto h = __builtin_amdgcn_cvt_pkrtz(a, b);   // v_cvt_pkrtz_f16_f32
    return __builtin_bit_cast(u32, h);
}

static __device__ __forceinline__ u32x2 swp(u32 a, u32 b){
    auto r = __builtin_amdgcn_permlane32_swap(a, b, false, false);
    return __builtin_bit_cast(u32x2, r);
}

// ---- fused prep: pack K and V^T into 32x32x16-MFMA fragment-major layout ----
// (unchanged — verified passing R4/R5/R6)
__global__ __launch_bounds__(256)
void kvprep(const float* __restrict__ Kg, const float* __restrict__ Vg,
            _Float16* __restrict__ kp, _Float16* __restrict__ vp){
    __shared__ float tV[64*65];
    const int t = blockIdx.x, bh = blockIdx.y, b = bh>>3, h = bh&7;
    const int tid = threadIdx.x;
#pragma unroll
    for(int i=0;i<4;++i){
        int idx = tid + i*256;
        int k = idx >> 4, d4 = (idx & 15)*4;
        float4 v = *(const float4*)(Vg + (((size_t)b*Ln + t*64 + k)*Hn + h)*Dn + d4);
        tV[k*65+d4+0]=v.x; tV[k*65+d4+1]=v.y;
        tV[k*65+d4+2]=v.z; tV[k*65+d4+3]=v.w;
    }
#pragma unroll
    for(int i=0;i<2;++i){
        int u = tid + i*256;
        int lane = u & 63, unit = u >> 6;
        int g = unit >> 2, cc = unit & 3;
        const float* src = Kg + (((size_t)b*Ln + t*64 + g*32 + (lane&31))*Hn + h)*Dn
                         + cc*16 + (lane>>5)*8;
        float4 a = *(const float4*)src;
        float4 c4 = *(const float4*)(src + 4);
        f16x8 o;
        o[0]=(_Float16)a.x;  o[1]=(_Float16)a.y;  o[2]=(_Float16)a.z;  o[3]=(_Float16)a.w;
        o[4]=(_Float16)c4.x; o[5]=(_Float16)c4.y; o[6]=(_Float16)c4.z; o[7]=(_Float16)c4.w;
        *(f16x8*)(kp + (size_t)bh*BH_STRIDE + (size_t)t*4096 + (size_t)u*8) = o;
    }
    __syncthreads();
#pragma unroll
    for(int i=0;i<2;++i){
        int u = tid + i*256;
        int lane = u & 63, unit = u >> 6;
        int g = unit >> 2, kh = (unit >> 1) & 1, dt = unit & 1;
        int krow = g*32 + kh*16 + (lane>>5)*8;
        int d = dt*32 + (lane&31);
        f16x8 o;
#pragma unroll
        for(int j=0;j<8;++j) o[j] = (_Float16)tV[(krow+j)*65 + d];
        *(f16x8*)(vp + (size_t)bh*BH_STRIDE + (size_t)t*4096 + (size_t)u*8) = o;
    }
}

// QK: 4-deep 32x32x16 chain from zero accumulator
static __device__ __forceinline__ f32x16 qk4(const f16x8 kf[4], const f16x8 qf[4]){
    f32x16 s;
#pragma unroll
    for(int r=0;r<16;++r) s[r]=0.f;
    s = __builtin_amdgcn_mfma_f32_32x32x16_f16(kf[0], qf[0], s, 0,0,0);
    s = __builtin_amdgcn_mfma_f32_32x32x16_f16(kf[1], qf[1], s, 0,0,0);
    s = __builtin_amdgcn_mfma_f32_32x32x16_f16(kf[2], qf[2], s, 0,0,0);
    s = __builtin_amdgcn_mfma_f32_32x32x16_f16(kf[3], qf[3], s, 0,0,0);
    return s;
}

// finish: exp2 -> pack (cvt_pkrtz + permlane32_swap) -> consistent-l via fdot2
// -> PV accumulate. Identical op set/order to R5 (bit-identical numerics).
static __device__ __forceinline__ void finish_pv(const f32x16& S, float& lac,
                                                 f32x16& o0, f32x16& o1,
                                                 const f16x8 vf[4]){
    f32x16 p;
#pragma unroll
    for(int r=0;r<16;++r) p[r] = __builtin_amdgcn_exp2f(S[r]);
    u32 A0 = pkf16(p[0],p[1]),   A1 = pkf16(p[2],p[3]);
    u32 B0 = pkf16(p[4],p[5]),   B1 = pkf16(p[6],p[7]);
    u32 C0 = pkf16(p[8],p[9]),   C1 = pkf16(p[10],p[11]);
    u32 D0 = pkf16(p[12],p[13]), D1 = pkf16(p[14],p[15]);
    u32x2 r0 = swp(A0,B0), r1 = swp(A1,B1);
    u32x2 r2 = swp(C0,D0), r3 = swp(C1,D1);
    u32x4 w0 = {r0.x, r1.x, r0.y, r1.y};   // keys [0,16) of this 32-key group
    u32x4 w1 = {r2.x, r3.x, r2.y, r3.y};   // keys [16,32)
    f16x8 pa0 = __builtin_bit_cast(f16x8, w0);
    f16x8 pa1 = __builtin_bit_cast(f16x8, w1);
    const f16x2 ones = {(_Float16)1.0f, (_Float16)1.0f};
#pragma unroll
    for(int j=0;j<4;++j){
        f16x2 c0 = {pa0[2*j], pa0[2*j+1]};
        f16x2 c1 = {pa1[2*j], pa1[2*j+1]};
        lac = __builtin_amdgcn_fdot2(c0, ones, lac, false);
        lac = __builtin_amdgcn_fdot2(c1, ones, lac, false);
    }
    // vf[j], j = kh*2+dt
    o0 = __builtin_amdgcn_mfma_f32_32x32x16_f16(pa0, vf[0], o0, 0,0,0);
    o0 = __builtin_amdgcn_mfma_f32_32x32x16_f16(pa1, vf[2], o0, 0,0,0);
    o1 = __builtin_amdgcn_mfma_f32_32x32x16_f16(pa0, vf[1], o1, 0,0,0);
    o1 = __builtin_amdgcn_mfma_f32_32x32x16_f16(pa1, vf[3], o1, 0,0,0);
}

// ---- main kernel: NO-LDS-staging version ----
// kp/vp are already in exact fragment order, so each wave loads its MFMA
// operands DIRECTLY from global (L2-resident by construction: all 32
// q-blocks of a bh map to one XCD; 2 bh x 2 MB = the 4 MB XCD L2).
// This deletes every __syncthreads in the main loop -> no phase convoy;
// waves free-run and their exp2/pack bursts overlap other waves' MFMAs.
// LDS now holds only the 35 KB epilogue buffer -> 4 blocks/CU
// (4 waves/SIMD, VGPR cap 128 >= R5's measured 112 usage).
// Compute order per wave is bit-identical to R5.
__global__ __launch_bounds__(256,4)
void attn_fwd(const float* __restrict__ Qg, float* __restrict__ Og,
              const _Float16* __restrict__ kp, const _Float16* __restrict__ vp){
    __shared__ __align__(16) float xo[128*68 + 128];   // epilogue combine

    const int tid  = threadIdx.x;
    const int lane = tid & 63, wv = tid >> 6;
    const int qh = wv & 1, kh2 = wv >> 1;
    const int l31 = lane & 31, hi = lane >> 5;
    const int bh = blockIdx.x, b = bh>>3, h = bh&7;
    const int q0 = blockIdx.y*128 + qh*64;

    const float c = 0.125f * 1.4426950408889634f;    // scale * log2(e)

    // Q B-frags: lane holds query=l31, d = cc*16 + hi*8 + j
    f16x8 qf[2][4];
#pragma unroll
    for(int qt=0;qt<2;++qt){
        const float* qrow = Qg + (((size_t)b*Ln + q0 + qt*32 + l31)*Hn + h)*Dn;
#pragma unroll
        for(int cc=0;cc<4;++cc){
            const float* p4 = qrow + cc*16 + hi*8;
            float4 x = *(const float4*)p4;
            float4 y = *(const float4*)(p4+4);
            f16x8 f;
            f[0]=(_Float16)(x.x*c); f[1]=(_Float16)(x.y*c);
            f[2]=(_Float16)(x.z*c); f[3]=(_Float16)(x.w*c);
            f[4]=(_Float16)(y.x*c); f[5]=(_Float16)(y.y*c);
            f[6]=(_Float16)(y.z*c); f[7]=(_Float16)(y.w*c);
            qf[qt][cc]=f;
        }
    }

    f32x16 o[2][2];
    float lac[2] = {0.f, 0.f};
#pragma unroll
    for(int qt=0;qt<2;++qt)
#pragma unroll
        for(int dt=0;dt<2;++dt)
#pragma unroll
            for(int r=0;r<16;++r) o[qt][dt][r]=0.f;

    // per-lane global base of this wave's 64-key half within each mega-tile:
    // mega-tile stride 16 KB; within it: kh2 half (8 KB), unit (1 KB), lane*16.
    const char* kgc = (const char*)(kp + (size_t)bh*BH_STRIDE) + kh2*8192 + lane*16;
    const char* vgc = (const char*)(vp + (size_t)bh*BH_STRIDE) + kh2*8192 + lane*16;

    for(int T=0; T<NMEGA; ++T){
        const char* Kb = kgc + (size_t)T*16384;
        const char* Vb = vgc + (size_t)T*16384;

        f16x8 kf0[4], vf0[4];
#pragma unroll
        for(int cc=0;cc<4;++cc) kf0[cc] = *(const f16x8*)(Kb + (cc<<10));
#pragma unroll
        for(int j=0;j<4;++j)    vf0[j]  = *(const f16x8*)(Vb + (j<<10));

        f32x16 S0 = qk4(kf0, qf[0]);          // unit (g0,qt0)
        f32x16 S1 = qk4(kf0, qf[1]);          // unit (g0,qt1)

        f16x8 kf1[4], vf1[4];
#pragma unroll
        for(int cc=0;cc<4;++cc) kf1[cc] = *(const f16x8*)(Kb + ((4+cc)<<10));
#pragma unroll
        for(int j=0;j<4;++j)    vf1[j]  = *(const f16x8*)(Vb + ((4+j)<<10));

        finish_pv(S0, lac[0], o[0][0], o[0][1], vf0);
        f32x16 S0b = qk4(kf1, qf[0]);         // unit (g1,qt0)
        finish_pv(S1, lac[1], o[1][0], o[1][1], vf0);
        f32x16 S1b = qk4(kf1, qf[1]);         // unit (g1,qt1)
        finish_pv(S0b, lac[0], o[0][0], o[0][1], vf1);
        finish_pv(S1b, lac[1], o[1][0], o[1][1], vf1);
    }

    // ---- reduce l within wave: lanes l and l+32 cover complementary key slots ----
    float lred[2];
#pragma unroll
    for(int qt=0;qt<2;++qt)
        lred[qt] = lac[qt] + __shfl_xor(lac[qt], 32, 64);

    // ---- epilogue: combine kh2 halves through LDS ----
    float* xl = xo + 128*68;
    if(kh2){
#pragma unroll
        for(int qt=0;qt<2;++qt){
#pragma unroll
            for(int dt=0;dt<2;++dt)
#pragma unroll
                for(int r=0;r<16;++r){
                    int qr = (r&3) + 8*(r>>2) + 4*hi;
                    xo[(qh*64 + qt*32 + qr)*68 + dt*32 + l31] = o[qt][dt][r];
                }
            if(hi==0) xl[qh*64 + qt*32 + l31] = lred[qt];
        }
    }
    __syncthreads();
    if(!kh2){
#pragma unroll
        for(int qt=0;qt<2;++qt){
            float inv = 1.0f/(lred[qt] + xl[qh*64 + qt*32 + l31]);
            float* ob = Og + (((size_t)b*Ln + q0 + qt*32)*Hn + h)*Dn;
#pragma unroll
            for(int r=0;r<16;++r){
                int qr = (r&3) + 8*(r>>2) + 4*hi;
                float invr = __shfl(inv, qr, 64);   // lane qr holds query qr's inv
#pragma unroll
                for(int dt=0;dt<2;++dt){
                    float val = o[qt][dt][r] + xo[(qh*64 + qt*32 + qr)*68 + dt*32 + l31];
                    ob[(size_t)qr*Hn*Dn + dt*32 + l31] = val*invr;
                }
            }
        }
    }
}

extern "C" void kernel_launch(void* const* d_in, const int* in_sizes, int n_in,
                              void* d_out, int out_size, void* d_ws, size_t ws_size,
                              hipStream_t stream) {
    const float* Q = (const float*)d_in[0];
    const float* K = (const float*)d_in[1];
    const float* V = (const float*)d_in[2];
    float* O = (float*)d_out;

    _Float16* kp = (_Float16*)d_ws;                        // 8 MB
    _Float16* vp = (_Float16*)((char*)d_ws + (8u<<20));    // 8 MB

    kvprep<<<dim3(64, 16), dim3(256), 0, stream>>>(K, V, kp, vp);
    attn_fwd<<<dim3(16, 32), dim3(256), 0, stream>>>(Q, O, kp, vp);
}

// Round 8
// 162.698 us; speedup vs baseline: 2.8290x; 2.8290x over previous
//
#include <hip/hip_runtime.h>

#define Bn 2
#define Ln 4096
#define Hn 8
#define Dn 64
#define NMEGA 32           // 128-key mega-tiles
#define BH_STRIDE 262144   // halves per bh in kp/vp

typedef float    f32x4  __attribute__((ext_vector_type(4)));
typedef float    f32x16 __attribute__((ext_vector_type(16)));
typedef _Float16 f16x2  __attribute__((ext_vector_type(2)));
typedef _Float16 f16x8  __attribute__((ext_vector_type(8)));
typedef unsigned int u32;
typedef u32 u32x2 __attribute__((ext_vector_type(2)));
typedef u32 u32x4 __attribute__((ext_vector_type(4)));

static __device__ __forceinline__ u32 pkf16(float a, float b){
    auto h = __builtin_amdgcn_cvt_pkrtz(a, b);   // v_cvt_pkrtz_f16_f32
    return __builtin_bit_cast(u32, h);
}

static __device__ __forceinline__ u32x2 swp(u32 a, u32 b){
    auto r = __builtin_amdgcn_permlane32_swap(a, b, false, false);
    return __builtin_bit_cast(u32x2, r);
}

// ---- fused prep: pack K and V^T into 32x32x16-MFMA fragment-major layout ----
// (unchanged — verified passing R4/R5/R6)
__global__ __launch_bounds__(256)
void kvprep(const float* __restrict__ Kg, const float* __restrict__ Vg,
            _Float16* __restrict__ kp, _Float16* __restrict__ vp){
    __shared__ float tV[64*65];
    const int t = blockIdx.x, bh = blockIdx.y, b = bh>>3, h = bh&7;
    const int tid = threadIdx.x;
#pragma unroll
    for(int i=0;i<4;++i){
        int idx = tid + i*256;
        int k = idx >> 4, d4 = (idx & 15)*4;
        float4 v = *(const float4*)(Vg + (((size_t)b*Ln + t*64 + k)*Hn + h)*Dn + d4);
        tV[k*65+d4+0]=v.x; tV[k*65+d4+1]=v.y;
        tV[k*65+d4+2]=v.z; tV[k*65+d4+3]=v.w;
    }
#pragma unroll
    for(int i=0;i<2;++i){
        int u = tid + i*256;
        int lane = u & 63, unit = u >> 6;
        int g = unit >> 2, cc = unit & 3;
        const float* src = Kg + (((size_t)b*Ln + t*64 + g*32 + (lane&31))*Hn + h)*Dn
                         + cc*16 + (lane>>5)*8;
        float4 a = *(const float4*)src;
        float4 c4 = *(const float4*)(src + 4);
        f16x8 o;
        o[0]=(_Float16)a.x;  o[1]=(_Float16)a.y;  o[2]=(_Float16)a.z;  o[3]=(_Float16)a.w;
        o[4]=(_Float16)c4.x; o[5]=(_Float16)c4.y; o[6]=(_Float16)c4.z; o[7]=(_Float16)c4.w;
        *(f16x8*)(kp + (size_t)bh*BH_STRIDE + (size_t)t*4096 + (size_t)u*8) = o;
    }
    __syncthreads();
#pragma unroll
    for(int i=0;i<2;++i){
        int u = tid + i*256;
        int lane = u & 63, unit = u >> 6;
        int g = unit >> 2, kh = (unit >> 1) & 1, dt = unit & 1;
        int krow = g*32 + kh*16 + (lane>>5)*8;
        int d = dt*32 + (lane&31);
        f16x8 o;
#pragma unroll
        for(int j=0;j<8;++j) o[j] = (_Float16)tV[(krow+j)*65 + d];
        *(f16x8*)(vp + (size_t)bh*BH_STRIDE + (size_t)t*4096 + (size_t)u*8) = o;
    }
}

// QK: 4-deep 32x32x16 chain from zero accumulator
static __device__ __forceinline__ f32x16 qk4(const f16x8 kf[4], const f16x8 qf[4]){
    f32x16 s;
#pragma unroll
    for(int r=0;r<16;++r) s[r]=0.f;
    s = __builtin_amdgcn_mfma_f32_32x32x16_f16(kf[0], qf[0], s, 0,0,0);
    s = __builtin_amdgcn_mfma_f32_32x32x16_f16(kf[1], qf[1], s, 0,0,0);
    s = __builtin_amdgcn_mfma_f32_32x32x16_f16(kf[2], qf[2], s, 0,0,0);
    s = __builtin_amdgcn_mfma_f32_32x32x16_f16(kf[3], qf[3], s, 0,0,0);
    return s;
}

// finish: exp2 -> pack (cvt_pkrtz + permlane32_swap) -> consistent-l via fdot2
// -> PV accumulate. Identical op set/order to R5 (bit-identical numerics).
static __device__ __forceinline__ void finish_pv(const f32x16& S, float& lac,
                                                 f32x16& o0, f32x16& o1,
                                                 const f16x8 vf[4]){
    f32x16 p;
#pragma unroll
    for(int r=0;r<16;++r) p[r] = __builtin_amdgcn_exp2f(S[r]);
    u32 A0 = pkf16(p[0],p[1]),   A1 = pkf16(p[2],p[3]);
    u32 B0 = pkf16(p[4],p[5]),   B1 = pkf16(p[6],p[7]);
    u32 C0 = pkf16(p[8],p[9]),   C1 = pkf16(p[10],p[11]);
    u32 D0 = pkf16(p[12],p[13]), D1 = pkf16(p[14],p[15]);
    u32x2 r0 = swp(A0,B0), r1 = swp(A1,B1);
    u32x2 r2 = swp(C0,D0), r3 = swp(C1,D1);
    u32x4 w0 = {r0.x, r1.x, r0.y, r1.y};   // keys [0,16) of this 32-key group
    u32x4 w1 = {r2.x, r3.x, r2.y, r3.y};   // keys [16,32)
    f16x8 pa0 = __builtin_bit_cast(f16x8, w0);
    f16x8 pa1 = __builtin_bit_cast(f16x8, w1);
    const f16x2 ones = {(_Float16)1.0f, (_Float16)1.0f};
#pragma unroll
    for(int j=0;j<4;++j){
        f16x2 c0 = {pa0[2*j], pa0[2*j+1]};
        f16x2 c1 = {pa1[2*j], pa1[2*j+1]};
        lac = __builtin_amdgcn_fdot2(c0, ones, lac, false);
        lac = __builtin_amdgcn_fdot2(c1, ones, lac, false);
    }
    // vf[j], j = kh*2+dt
    o0 = __builtin_amdgcn_mfma_f32_32x32x16_f16(pa0, vf[0], o0, 0,0,0);
    o0 = __builtin_amdgcn_mfma_f32_32x32x16_f16(pa1, vf[2], o0, 0,0,0);
    o1 = __builtin_amdgcn_mfma_f32_32x32x16_f16(pa0, vf[1], o1, 0,0,0);
    o1 = __builtin_amdgcn_mfma_f32_32x32x16_f16(pa1, vf[3], o1, 0,0,0);
}

// ---- main kernel: NO-LDS-staging, free-running waves ----
// kp/vp are already in exact fragment order, so each wave loads its MFMA
// operands DIRECTLY from global (L2-resident: all 32 q-blocks of a bh map
// to XCD bh%8; 2 bh x 2 MB fits the 4 MB XCD L2). No __syncthreads in the
// main loop -> no phase convoy; waves free-run and their exp2/pack bursts
// overlap other waves' MFMAs. LDS = 35 KB epilogue only -> 4 blocks/CU.
// __launch_bounds__ 2nd arg EMPIRICAL MAP (R2/R5/R6/R7): arg=4 -> 64-VGPR
// cap (spills ~1.7GB, 417us); arg=2 -> 128 cap (R5 needed 112, clean).
// So (256,2): 128 cap; 112 VGPR + 35 KB LDS both allow 4 blocks/CU.
// Compute order per wave is bit-identical to R5.
__global__ __launch_bounds__(256,2)
void attn_fwd(const float* __restrict__ Qg, float* __restrict__ Og,
              const _Float16* __restrict__ kp, const _Float16* __restrict__ vp){
    __shared__ __align__(16) float xo[128*68 + 128];   // epilogue combine

    const int tid  = threadIdx.x;
    const int lane = tid & 63, wv = tid >> 6;
    const int qh = wv & 1, kh2 = wv >> 1;
    const int l31 = lane & 31, hi = lane >> 5;
    const int bh = blockIdx.x, b = bh>>3, h = bh&7;
    const int q0 = blockIdx.y*128 + qh*64;

    const float c = 0.125f * 1.4426950408889634f;    // scale * log2(e)

    // Q B-frags: lane holds query=l31, d = cc*16 + hi*8 + j
    f16x8 qf[2][4];
#pragma unroll
    for(int qt=0;qt<2;++qt){
        const float* qrow = Qg + (((size_t)b*Ln + q0 + qt*32 + l31)*Hn + h)*Dn;
#pragma unroll
        for(int cc=0;cc<4;++cc){
            const float* p4 = qrow + cc*16 + hi*8;
            float4 x = *(const float4*)p4;
            float4 y = *(const float4*)(p4+4);
            f16x8 f;
            f[0]=(_Float16)(x.x*c); f[1]=(_Float16)(x.y*c);
            f[2]=(_Float16)(x.z*c); f[3]=(_Float16)(x.w*c);
            f[4]=(_Float16)(y.x*c); f[5]=(_Float16)(y.y*c);
            f[6]=(_Float16)(y.z*c); f[7]=(_Float16)(y.w*c);
            qf[qt][cc]=f;
        }
    }

    f32x16 o[2][2];
    float lac[2] = {0.f, 0.f};
#pragma unroll
    for(int qt=0;qt<2;++qt)
#pragma unroll
        for(int dt=0;dt<2;++dt)
#pragma unroll
            for(int r=0;r<16;++r) o[qt][dt][r]=0.f;

    // per-lane global base of this wave's 64-key half within each mega-tile:
    // mega-tile stride 16 KB; within it: kh2 half (8 KB), unit (1 KB), lane*16.
    const char* kgc = (const char*)(kp + (size_t)bh*BH_STRIDE) + kh2*8192 + lane*16;
    const char* vgc = (const char*)(vp + (size_t)bh*BH_STRIDE) + kh2*8192 + lane*16;

    for(int T=0; T<NMEGA; ++T){
        const char* Kb = kgc + (size_t)T*16384;
        const char* Vb = vgc + (size_t)T*16384;

        f16x8 kf0[4], vf0[4];
#pragma unroll
        for(int cc=0;cc<4;++cc) kf0[cc] = *(const f16x8*)(Kb + (cc<<10));
#pragma unroll
        for(int j=0;j<4;++j)    vf0[j]  = *(const f16x8*)(Vb + (j<<10));

        f32x16 S0 = qk4(kf0, qf[0]);          // unit (g0,qt0)
        f32x16 S1 = qk4(kf0, qf[1]);          // unit (g0,qt1)

        f16x8 kf1[4], vf1[4];
#pragma unroll
        for(int cc=0;cc<4;++cc) kf1[cc] = *(const f16x8*)(Kb + ((4+cc)<<10));
#pragma unroll
        for(int j=0;j<4;++j)    vf1[j]  = *(const f16x8*)(Vb + ((4+j)<<10));

        finish_pv(S0, lac[0], o[0][0], o[0][1], vf0);
        f32x16 S0b = qk4(kf1, qf[0]);         // unit (g1,qt0)
        finish_pv(S1, lac[1], o[1][0], o[1][1], vf0);
        f32x16 S1b = qk4(kf1, qf[1]);         // unit (g1,qt1)
        finish_pv(S0b, lac[0], o[0][0], o[0][1], vf1);
        finish_pv(S1b, lac[1], o[1][0], o[1][1], vf1);
    }

    // ---- reduce l within wave: lanes l and l+32 cover complementary key slots ----
    float lred[2];
#pragma unroll
    for(int qt=0;qt<2;++qt)
        lred[qt] = lac[qt] + __shfl_xor(lac[qt], 32, 64);

    // ---- epilogue: combine kh2 halves through LDS ----
    float* xl = xo + 128*68;
    if(kh2){
#pragma unroll
        for(int qt=0;qt<2;++qt){
#pragma unroll
            for(int dt=0;dt<2;++dt)
#pragma unroll
                for(int r=0;r<16;++r){
                    int qr = (r&3) + 8*(r>>2) + 4*hi;
                    xo[(qh*64 + qt*32 + qr)*68 + dt*32 + l31] = o[qt][dt][r];
                }
            if(hi==0) xl[qh*64 + qt*32 + l31] = lred[qt];
        }
    }
    __syncthreads();
    if(!kh2){
#pragma unroll
        for(int qt=0;qt<2;++qt){
            float inv = 1.0f/(lred[qt] + xl[qh*64 + qt*32 + l31]);
            float* ob = Og + (((size_t)b*Ln + q0 + qt*32)*Hn + h)*Dn;
#pragma unroll
            for(int r=0;r<16;++r){
                int qr = (r&3) + 8*(r>>2) + 4*hi;
                float invr = __shfl(inv, qr, 64);   // lane qr holds query qr's inv
#pragma unroll
                for(int dt=0;dt<2;++dt){
                    float val = o[qt][dt][r] + xo[(qh*64 + qt*32 + qr)*68 + dt*32 + l31];
                    ob[(size_t)qr*Hn*Dn + dt*32 + l31] = val*invr;
                }
            }
        }
    }
}

extern "C" void kernel_launch(void* const* d_in, const int* in_sizes, int n_in,
                              void* d_out, int out_size, void* d_ws, size_t ws_size,
                              hipStream_t stream) {
    const float* Q = (const float*)d_in[0];
    const float* K = (const float*)d_in[1];
    const float* V = (const float*)d_in[2];
    float* O = (float*)d_out;

    _Float16* kp = (_Float16*)d_ws;                        // 8 MB
    _Float16* vp = (_Float16*)((char*)d_ws + (8u<<20));    // 8 MB

    kvprep<<<dim3(64, 16), dim3(256), 0, stream>>>(K, V, kp, vp);
    attn_fwd<<<dim3(16, 32), dim3(256), 0, stream>>>(Q, O, kp, vp);
}